// Round 3
// baseline (411.193 us; speedup 1.0000x reference)
//
#include <hip/hip_runtime.h>
#include <hip/hip_fp16.h>

// Deformable RoI pooling (MMCV-style), forward only.
// features: (B=8, C=256, H=168, W=168) fp32 = 231 MB
// rois:     (N=512, 5)  [bidx, x1, y1, x2, y2]
// offset:   (N=512, 2, PH=7, PW=7)
// out:      (N, C, PH, PW) fp32
//
// Round 7:
//  - main kernel pipelined: each block owns PPB_=4 channels; next plane's
//    global loads are ISSUED before sampling the current plane (T14 split:
//    issue-early / convert+ds_write-late), so HBM latency hides under the
//    LDS gather. Grid 64x8=512 blocks (2/CU, all resident, one wavefront
//    of blocks instead of four).
//  - inactive lanes (pad lanes + tail chunks) skip desc loads + LDS reads.
//  - folded fp32 weights + clamp-free 4-tap reads vs zero-padded fp16 plane
//    (round-6 algorithm, verified absmax 0.015625).

#define PH_ 7
#define PW_ 7
#define SPP_ 2
#define SS_ 0.0625f
#define TRANS_STD_ 0.1f
#define B_ 8
#define C_ 256
#define H_ 168
#define W_ 168
#define N_ 512
#define HW_ (H_ * W_)            // 28224
#define HW4_ (HW_ / 4)           // 7056 float4s per plane
#define BINS_ (PH_ * PW_)        // 49
#define NSUB_ (SPP_ * SPP_)      // 4
#define BLK_ 1024
#define RPC_ 20                  // rois per chunk (20*49 = 980 <= 1024)
#define PLN_ (HW_ + W_ + 4)      // zero-padded plane (max tap idx = HW_+W_)
#define PPB_ 4                   // channels (planes) per block
#define NLD_ 7                   // float4 loads per thread per plane

// ws layout (ints):
//   counts[8] | lists[8][512] | descA uint4[N][BINS] | descW float4[N][BINS][NSUB]
#define WS_LIST_OFF_   B_
#define WS_DESCA_OFF_I (B_ + B_ * N_)                    // 4104 ints (16B-aligned)
#define DESCA_INTS_    (N_ * BINS_ * 4)                  // 100352 ints
#define WS_DESCW_OFF_I (WS_DESCA_OFF_I + DESCA_INTS_)    // 104456 ints (16B-aligned)
#define DESCW_FLOATS_  (N_ * BINS_ * NSUB_ * 4)          // 401408 floats
#define WS_NEEDED_     ((size_t)(WS_DESCW_OFF_I + DESCW_FLOATS_) * 4)

// ---------------- prologue 1: bucket rois by image ----------------
__global__ __launch_bounds__(512) void build_roi_lists(
    const float* __restrict__ rois, int* __restrict__ ws)
{
    const int r = threadIdx.x;              // 512 threads, 1 block
    if (r < B_) ws[r] = 0;                  // ws is poisoned each call
    __syncthreads();
    const int b = (int)rois[r * 5 + 0];
    const int pos = atomicAdd(&ws[b], 1);
    ws[WS_LIST_OFF_ + b * N_ + pos] = r;
}

// ---------------- prologue 2: folded-weight descriptors ----------------
// one block per roi; lanes 0..48 = bins.
__global__ __launch_bounds__(64) void build_desc(
    const float* __restrict__ rois,
    const float* __restrict__ offset,
    int* __restrict__ ws)
{
    const int r   = blockIdx.x;
    const int bin = threadIdx.x;
    if (bin >= BINS_) return;
    const int ph = bin / PW_;
    const int pw = bin - ph * PW_;

    const float x1r = rois[r * 5 + 1];
    const float y1r = rois[r * 5 + 2];
    const float x2r = rois[r * 5 + 3];
    const float y2r = rois[r * 5 + 4];

    const float sw    = x1r * SS_ - 0.5f;
    const float sh    = y1r * SS_ - 0.5f;
    const float rw    = fmaxf((x2r + 1.0f) * SS_ - 0.5f - sw, 0.1f);
    const float rh    = fmaxf((y2r + 1.0f) * SS_ - 0.5f - sh, 0.1f);
    const float bin_w = rw * (1.0f / PW_);
    const float bin_h = rh * (1.0f / PH_);
    const float sub_w = bin_w * (1.0f / SPP_);
    const float sub_h = bin_h * (1.0f / SPP_);

    const float offx = offset[((r * 2 + 0) * PH_ + ph) * PW_ + pw] * TRANS_STD_;
    const float offy = offset[((r * 2 + 1) * PH_ + ph) * PW_ + pw] * TRANS_STD_;

    const float bx = sw + (float)pw * bin_w + offx * rw;
    const float by = sh + (float)ph * bin_h + offy * rh;

    unsigned idx[NSUB_];
    float w00[NSUB_], w01[NSUB_], w10[NSUB_], w11[NSUB_];
    int   vals[NSUB_];
    int   cnt = 0;
#pragma unroll
    for (int s = 0; s < NSUB_; ++s) {
        const int ihs = s >> 1;             // sub index order: (ih, iw)
        const int iws = s & 1;
        const float x = bx + ((float)iws + 0.5f) * sub_w;
        const float y = by + ((float)ihs + 0.5f) * sub_h;
        const int valid = (x > -0.5f) && (x < (float)W_ - 0.5f) &&
                          (y > -0.5f) && (y < (float)H_ - 0.5f);
        const float xc = fminf(fmaxf(x, 0.0f), (float)(W_ - 1));
        const float yc = fminf(fmaxf(y, 0.0f), (float)(H_ - 1));
        const float x0f = floorf(xc);
        const float y0f = floorf(yc);
        const int x0 = (int)x0f;
        const int y0 = (int)y0f;
        const float lx = xc - x0f;
        const float ly = yc - y0f;
        // NOTE: if lx>0 then x0 <= W-2 (floor of xc<W-1), so the +1 neighbor
        // is in-range whenever its weight is nonzero; same for ly/y0.
        idx[s] = (unsigned)(y0 * W_ + x0);
        w00[s] = (1.0f - ly) * (1.0f - lx);
        w01[s] = (1.0f - ly) * lx;
        w10[s] = ly * (1.0f - lx);
        w11[s] = ly * lx;
        vals[s] = valid;
        cnt += valid;
    }
    const float inv = (cnt > 0) ? (1.0f / (float)cnt) : 0.0f;

    uint4*  descA = reinterpret_cast<uint4*> (ws + WS_DESCA_OFF_I);
    float4* descW = reinterpret_cast<float4*>(ws + WS_DESCW_OFF_I);

    const int rb = r * BINS_ + bin;
#pragma unroll
    for (int s = 0; s < NSUB_; ++s) {
        const float f = vals[s] ? inv : 0.0f;
        float4 w;
        w.x = w00[s] * f;
        w.y = w01[s] * f;
        w.z = w10[s] * f;
        w.w = w11[s] * f;
        descW[(size_t)rb * NSUB_ + s] = w;
    }
    uint4 a4;
    a4.x = idx[0]; a4.y = idx[1]; a4.z = idx[2]; a4.w = idx[3];
    descA[rb] = a4;
}

// ---------------- main kernel (pipelined over PPB_ planes) ----------------

#define LOAD_PLANE(cc)                                               \
    do {                                                             \
        const float4* __restrict__ f4 = fbase + (size_t)(cc) * HW4_; \
        _Pragma("unroll")                                            \
        for (int i = 0; i < NLD_; ++i) {                             \
            const int ii = tid + i * BLK_;                           \
            v[i] = f4[ii < HW4_ ? ii : 0];                           \
        }                                                            \
    } while (0)

#define STORE_PLANE()                                                \
    do {                                                             \
        _Pragma("unroll")                                            \
        for (int i = 0; i < NLD_; ++i) {                             \
            const int ii = tid + i * BLK_;                           \
            if (ii < HW4_) {                                         \
                union { __half2 h[2]; float2 f2; } u;                \
                u.h[0].x = __float2half(v[i].x);                     \
                u.h[0].y = __float2half(v[i].y);                     \
                u.h[1].x = __float2half(v[i].z);                     \
                u.h[1].y = __float2half(v[i].w);                     \
                *reinterpret_cast<float2*>(&plane[ii * 4]) = u.f2;   \
            }                                                        \
        }                                                            \
    } while (0)

__global__ __launch_bounds__(BLK_, 8) void droi_pool_lds(
    const float* __restrict__ features,
    float* __restrict__ out,
    const int* __restrict__ ws)
{
    __shared__ __half plane[PLN_];          // 56,792 B -> 2 blocks/CU @1024 thr

    const int c0  = blockIdx.x * PPB_;      // first channel of this block
    const int b   = blockIdx.y;             // image
    const int tid = threadIdx.x;

    const float4* __restrict__ fbase =
        reinterpret_cast<const float4*>(features + (size_t)b * C_ * HW_);

    float4 v[NLD_];

    // ---- prologue: plane c0 -> LDS; zero-pad tail once ----
    LOAD_PLANE(c0);
    for (int i = HW_ + tid; i < PLN_; i += BLK_) plane[i] = __float2half(0.0f);
    STORE_PLANE();
    __syncthreads();

    const int cnt_b = ws[b];
    const int* __restrict__ list = ws + WS_LIST_OFF_ + b * N_;
    const uint4* __restrict__ descA =
        reinterpret_cast<const uint4*>(ws + WS_DESCA_OFF_I);
    const float4* __restrict__ descW =
        reinterpret_cast<const float4*>(ws + WS_DESCW_OFF_I);

    const int q   = tid / BINS_;            // roi slot within chunk
    const int bin = tid - q * BINS_;        // 0..48
    const bool lane_ok = (q < RPC_);

#pragma unroll
    for (int p = 0; p < PPB_; ++p) {
        const int c = c0 + p;

        // issue next plane's global loads BEFORE sampling: their ~900-cycle
        // latency hides under phase 2; the compiler's vmcnt(0) drain sits at
        // the __syncthreads() below, after sampling is done.
        if (p + 1 < PPB_) LOAD_PLANE(c + 1);

        // ---- phase 2: rois of image b sample plane c via descriptors ----
        for (int base = 0; base < cnt_b; base += RPC_) {
            const int idx    = base + q;
            const bool active = lane_ok && (idx < cnt_b);
            if (active) {
                const int r  = list[idx];
                const int rb = r * BINS_ + bin;

                const uint4 a4 = descA[rb];
                const float4* __restrict__ wp = descW + (size_t)rb * NSUB_;

                float acc = 0.0f;
#pragma unroll
                for (int s = 0; s < NSUB_; ++s) {
                    const float4 w = wp[s];
                    const int a = (int)((&a4.x)[s]);
                    const float f00 = __half2float(plane[a]);
                    const float f01 = __half2float(plane[a + 1]);
                    const float f10 = __half2float(plane[a + W_]);
                    const float f11 = __half2float(plane[a + W_ + 1]);
                    acc += w.x * f00 + w.y * f01 + w.z * f10 + w.w * f11;
                }
                out[((size_t)r * C_ + c) * BINS_ + bin] = acc;
            }
        }

        __syncthreads();                    // all waves done reading plane c
        if (p + 1 < PPB_) STORE_PLANE();    // convert + ds_write plane c+1
        __syncthreads();                    // plane c+1 visible
    }
}

// ---------------- fallback (round-1 kernel) if ws too small ----------------
__global__ __launch_bounds__(64) void droi_pool_fallback(
    const float* __restrict__ features,
    const float* __restrict__ rois,
    const float* __restrict__ offset,
    float* __restrict__ out)
{
    const int blk  = blockIdx.x;
    const int n    = blk >> 8;
    const int c    = blk & 255;
    const int lane = threadIdx.x;
    if (lane >= BINS_) return;
    const int ph = lane / PW_;
    const int pw = lane % PW_;

    const float r0  = rois[n * 5 + 0];
    const float x1r = rois[n * 5 + 1];
    const float y1r = rois[n * 5 + 2];
    const float x2r = rois[n * 5 + 3];
    const float y2r = rois[n * 5 + 4];
    const int   b   = (int)r0;

    const float sw    = x1r * SS_ - 0.5f;
    const float sh    = y1r * SS_ - 0.5f;
    const float rw    = fmaxf((x2r + 1.0f) * SS_ - 0.5f - sw, 0.1f);
    const float rh    = fmaxf((y2r + 1.0f) * SS_ - 0.5f - sh, 0.1f);
    const float bin_w = rw / PW_;
    const float bin_h = rh / PH_;
    const float sub_w = bin_w / SPP_;
    const float sub_h = bin_h / SPP_;

    const float offx = offset[((n * 2 + 0) * PH_ + ph) * PW_ + pw] * TRANS_STD_;
    const float offy = offset[((n * 2 + 1) * PH_ + ph) * PW_ + pw] * TRANS_STD_;

    const float bx = sw + (float)pw * bin_w + offx * rw;
    const float by = sh + (float)ph * bin_h + offy * rh;

    const float* __restrict__ f =
        features + (size_t)(b * C_ + c) * (size_t)HW_;

    float s = 0.0f;
    int cnt = 0;
#pragma unroll
    for (int ihs = 0; ihs < SPP_; ++ihs) {
#pragma unroll
        for (int iws = 0; iws < SPP_; ++iws) {
            const float x = bx + ((float)iws + 0.5f) * sub_w;
            const float y = by + ((float)ihs + 0.5f) * sub_h;
            const bool valid = (x > -0.5f) && (x < (float)W_ - 0.5f) &&
                               (y > -0.5f) && (y < (float)H_ - 0.5f);
            const float xc = fminf(fmaxf(x, 0.0f), (float)(W_ - 1));
            const float yc = fminf(fmaxf(y, 0.0f), (float)(H_ - 1));
            const float x0f = floorf(xc);
            const float y0f = floorf(yc);
            const float lx = xc - x0f;
            const float ly = yc - y0f;
            const int x0 = (int)x0f;
            const int y0 = (int)y0f;
            const int x1i = min(x0 + 1, W_ - 1);
            const int y1i = min(y0 + 1, H_ - 1);
            const float f00 = f[y0  * W_ + x0 ];
            const float f01 = f[y0  * W_ + x1i];
            const float f10 = f[y1i * W_ + x0 ];
            const float f11 = f[y1i * W_ + x1i];
            const float v = (1.0f - ly) * (1.0f - lx) * f00 +
                            (1.0f - ly) * lx          * f01 +
                            ly          * (1.0f - lx) * f10 +
                            ly          * lx          * f11;
            if (valid) { s += v; cnt += 1; }
        }
    }
    const float res = (cnt > 0) ? (s / (float)cnt) : 0.0f;
    out[(size_t)(n * C_ + c) * BINS_ + lane] = res;
}

extern "C" void kernel_launch(void* const* d_in, const int* in_sizes, int n_in,
                              void* d_out, int out_size, void* d_ws, size_t ws_size,
                              hipStream_t stream) {
    const float* features = (const float*)d_in[0];
    const float* rois     = (const float*)d_in[1];
    const float* offset   = (const float*)d_in[2];
    float*       out      = (float*)d_out;

    if (ws_size >= WS_NEEDED_) {
        int* ws = (int*)d_ws;
        hipLaunchKernelGGL(build_roi_lists, dim3(1), dim3(N_), 0, stream,
                           rois, ws);
        hipLaunchKernelGGL(build_desc, dim3(N_), dim3(64), 0, stream,
                           rois, offset, ws);
        // grid: x = channel-group (64), y = image (8); 512 blocks, 2/CU,
        // all resident; each block pipelines PPB_=4 planes.
        hipLaunchKernelGGL(droi_pool_lds, dim3(C_ / PPB_, B_), dim3(BLK_),
                           0, stream, features, out, ws);
    } else {
        hipLaunchKernelGGL(droi_pool_fallback, dim3(N_ * C_), dim3(64), 0, stream,
                           features, rois, offset, out);
    }
}